// Round 7
// baseline (874.753 us; speedup 1.0000x reference)
//
#include <hip/hip_runtime.h>
#include <stdint.h>

#define N_NODES 100000
#define N_EDGES 1600000
#define NB_SCAN 391   // ceil(N_NODES/256)

// Round 22. r21 A/B results: nt-store hurt scatter (112->121, WRITE still
// 101MB) -> plain stores; 4-edge agg unroll hurt (fuse_heads 111->120) ->
// back to 2-edge pipeline. New levers:
// (1) BF path scatter writes 8B records {src, a1|a0 bf16 bits} (bitwise-
//     exact) -> staging 12.8MB, 8 rec/line -> L2 write-combining merges.
// (2) degree-sorted node perm (counting sort, 256 bins) -> the 4 groups of
//     a wave get equal-degree nodes -> agg loop runs deg not max4(deg)
//     iterations (~20% fewer). Per-node math identical -> absmax unchanged.

__device__ __forceinline__ float bf2f(unsigned short s) {
    return __uint_as_float(((unsigned)s) << 16);
}
__device__ __forceinline__ unsigned short f2bf(float f) {
    unsigned u = __float_as_uint(f);
    u += 0x7fffu + ((u >> 16) & 1u);
    return (unsigned short)(u >> 16);
}
template <bool BF16>
__device__ __forceinline__ float LD(const void* p, size_t i) {
    if (BF16) return bf2f(((const unsigned short*)p)[i]);
    return ((const float*)p)[i];
}

// ---------------- dtype detection (proven) ----------------
__global__ void k_detect(const unsigned* __restrict__ xw, int* __restrict__ flag) {
    __shared__ int tot;
    if (threadIdx.x == 0) tot = 0;
    __syncthreads();
    int hit = 0;
    for (int i = threadIdx.x; i < 1024; i += 256) {
        unsigned e = (xw[i] >> 7) & 0xFFu;
        if (e >= 110u && e <= 135u) hit++;
    }
    atomicAdd(&tot, hit);
    __syncthreads();
    if (threadIdx.x == 0) *flag = (tot >= 512) ? 1 : 0;
}

// ---------------- CSR build ----------------

__global__ void k_hist(const int* __restrict__ ei, int* __restrict__ deg) {
    int e = blockIdx.x * 256 + threadIdx.x;
    if (e < N_EDGES) atomicAdd(&deg[ei[N_EDGES + e]], 1);
}

__global__ void k_scan_partial(const int* __restrict__ deg, int* __restrict__ bsum) {
    int t = threadIdx.x;
    int i = blockIdx.x * 256 + t;
    int v = (i < N_NODES) ? deg[i] : 0;
    for (int off = 32; off > 0; off >>= 1) v += __shfl_down(v, off, 64);
    __shared__ int ws4[4];
    if ((t & 63) == 0) ws4[t >> 6] = v;
    __syncthreads();
    if (t == 0) bsum[blockIdx.x] = ws4[0] + ws4[1] + ws4[2] + ws4[3];
}

__global__ void k_scan_mid(const int* __restrict__ bsum, int* __restrict__ boff) {
    __shared__ int s[512];
    int t = threadIdx.x;
    int v = (t < NB_SCAN) ? bsum[t] : 0;
    s[t] = v;
    __syncthreads();
    for (int off = 1; off < 512; off <<= 1) {
        int x = (t >= off) ? s[t - off] : 0;
        __syncthreads();
        s[t] += x;
        __syncthreads();
    }
    if (t < NB_SCAN) boff[t] = s[t] - v;   // exclusive
}

__global__ void k_scan_final(const int* __restrict__ deg, const int* __restrict__ boff,
                             int* __restrict__ row_start, int* __restrict__ cursor) {
    __shared__ int s[256];
    int t = threadIdx.x;
    int i = blockIdx.x * 256 + t;
    int v = (i < N_NODES) ? deg[i] : 0;
    s[t] = v;
    __syncthreads();
    for (int off = 1; off < 256; off <<= 1) {
        int x = (t >= off) ? s[t - off] : 0;
        __syncthreads();
        s[t] += x;
        __syncthreads();
    }
    if (i < N_NODES) {
        int rs = boff[blockIdx.x] + s[t] - v;
        row_start[i] = rs;
        cursor[i] = rs;
    }
}

// ---------------- degree counting sort (256 bins) ----------------

__global__ void k_deg_hist(const int* __restrict__ deg, int* __restrict__ blkhist) {
    __shared__ int h[256];
    int t = threadIdx.x;
    h[t] = 0;
    __syncthreads();
    int i = blockIdx.x * 256 + t;
    if (i < N_NODES) atomicAdd(&h[min(deg[i], 255)], 1);
    __syncthreads();
    blkhist[blockIdx.x * 256 + t] = h[t];
}

__global__ void k_bin_scan(const int* __restrict__ blkhist, int* __restrict__ bincur) {
    __shared__ int s[256];
    int t = threadIdx.x;
    int sum = 0;
    for (int b = 0; b < NB_SCAN; b++) sum += blkhist[b * 256 + t];
    s[t] = sum;
    __syncthreads();
    for (int off = 1; off < 256; off <<= 1) {
        int x = (t >= off) ? s[t - off] : 0;
        __syncthreads();
        s[t] += x;
        __syncthreads();
    }
    bincur[t] = s[t] - sum;   // exclusive offset
}

__global__ void k_perm(const int* __restrict__ deg, int* __restrict__ bincur,
                       int* __restrict__ perm) {
    int i = blockIdx.x * 256 + threadIdx.x;
    if (i < N_NODES) {
        int b = min(deg[i], 255);
        int pos = atomicAdd(&bincur[b], 1);
        perm[pos] = i;
    }
}

// ---------------- CSR scatter ----------------
// BF path: 8B record {src, (a1<<16)|a0 raw bf16 bits} - bitwise exact.
// FP path: 16B record {src, a0bits, a1bits, 0}.

__device__ void scatter_bf(const int* __restrict__ ei, const unsigned short* __restrict__ ea,
                           int* __restrict__ cursor, uint2* __restrict__ rec8) {
    int e = blockIdx.x * 256 + threadIdx.x;   // grid exact: 6250*256 = 1.6M
    int s = ei[e];
    int d = ei[N_EDGES + e];
    unsigned a0 = ea[(size_t)e * 2];
    unsigned a1 = ea[(size_t)e * 2 + 1];
    int slot = atomicAdd(&cursor[d], 1);
    rec8[slot] = make_uint2((unsigned)s, a0 | (a1 << 16));
}

__device__ void scatter_fp(const int* __restrict__ ei, const float* __restrict__ ea,
                           int* __restrict__ cursor, uint4* __restrict__ rec16) {
    int e = blockIdx.x * 256 + threadIdx.x;
    int s = ei[e];
    int d = ei[N_EDGES + e];
    float a0 = ea[(size_t)e * 2];
    float a1 = ea[(size_t)e * 2 + 1];
    int slot = atomicAdd(&cursor[d], 1);
    rec16[slot] = make_uint4((unsigned)s, __float_as_uint(a0), __float_as_uint(a1), 0u);
}

__global__ void k_scatter(const int* __restrict__ flag, const int* ei, const void* ea,
                          int* cursor, void* staging) {
    if (*flag) scatter_bf(ei, (const unsigned short*)ea, cursor, (uint2*)staging);
    else       scatter_fp(ei, (const float*)ea, cursor, (uint4*)staging);
}

// ---------------- edge-MLP pass: slot-ordered, fully coalesced ----------------

template <bool BF>
__device__ __forceinline__ void ew_body(const void* __restrict__ staging,
                                        const void* ew1, const void* eb1,
                                        const void* ew2, const void* eb2,
                                        int* __restrict__ csr_src,
                                        float* __restrict__ ew4,
                                        float (*w1)[2][16], float (*b1)[16],
                                        float (*w2)[16], float* b2) {
    int t = threadIdx.x;
    if (t < 128) ((float*)w1)[t] = LD<BF>(ew1, t);
    else if (t < 192) ((float*)b1)[t - 128] = LD<BF>(eb1, t - 128);
    else ((float*)w2)[t - 192] = LD<BF>(ew2, t - 192);
    if (t < 4) b2[t] = LD<BF>(eb2, t);
    __syncthreads();

    int e = blockIdx.x * 256 + t;   // grid exact: 6250*256 = 1.6M
    float a0, a1;
    if (BF) {
        uint2 u = ((const uint2*)staging)[e];
        csr_src[e] = (int)u.x;
        a0 = bf2f((unsigned short)(u.y & 0xffffu));
        a1 = bf2f((unsigned short)(u.y >> 16));
    } else {
        uint4 u = ((const uint4*)staging)[e];
        csr_src[e] = (int)u.x;
        a0 = __uint_as_float(u.y);
        a1 = __uint_as_float(u.z);
    }
    #pragma unroll
    for (int l = 0; l < 4; l++) {
        float z = b2[l];
        #pragma unroll
        for (int q = 0; q < 16; q++) {
            float hj = fmaf(a0, w1[l][0][q], fmaf(a1, w1[l][1][q], b1[l][q]));
            z = fmaf(fmaxf(hj, 0.f), w2[l][q], z);
        }
        ew4[(size_t)l * N_EDGES + e] = 1.f / (1.f + expf(-z));
    }
}

__global__ void k_ew(const int* __restrict__ flag, const void* __restrict__ staging,
                     const void* ew1, const void* eb1, const void* ew2, const void* eb2,
                     int* csr_src, float* ew4) {
    __shared__ float w1[4][2][16], b1[4][16], w2[4][16], b2[4];
    if (*flag) ew_body<true>(staging, ew1, eb1, ew2, eb2, csr_src, ew4, w1, b1, w2, b2);
    else       ew_body<false>(staging, ew1, eb1, ew2, eb2, csr_src, ew4, w1, b1, w2, b2);
}

// ---------------- layer 0 dense ----------------

template <bool BF>
__device__ __forceinline__ void dense0_body(const void* __restrict__ x,
                                            const void* __restrict__ W,
                                            const void* __restrict__ b,
                                            unsigned short* __restrict__ h,
                                            float* Wl, float (*xl)[32]) {
    int t = threadIdx.x, w = t >> 6, lane = t & 63;
    for (int i = t; i < 32 * 64; i += 256) Wl[i] = LD<BF>(W, i);
    int v0 = blockIdx.x * 16 + w * 4;
    if (lane < 32) {
        #pragma unroll
        for (int n = 0; n < 4; n++)
            xl[w * 4 + n][lane] = LD<BF>(x, (size_t)(v0 + n) * 32 + lane);
    }
    __syncthreads();
    float bias = LD<BF>(b, lane);
    float a0 = bias, a1 = bias, a2 = bias, a3 = bias;
    #pragma unroll 8
    for (int k = 0; k < 32; k++) {
        float wv = Wl[k * 64 + lane];
        a0 = fmaf(xl[w * 4 + 0][k], wv, a0);
        a1 = fmaf(xl[w * 4 + 1][k], wv, a1);
        a2 = fmaf(xl[w * 4 + 2][k], wv, a2);
        a3 = fmaf(xl[w * 4 + 3][k], wv, a3);
    }
    h[(size_t)(v0 + 0) * 64 + lane] = f2bf(a0);
    h[(size_t)(v0 + 1) * 64 + lane] = f2bf(a1);
    h[(size_t)(v0 + 2) * 64 + lane] = f2bf(a2);
    h[(size_t)(v0 + 3) * 64 + lane] = f2bf(a3);
}

__global__ void k_dense0(const int* __restrict__ flag, const void* x, const void* W,
                         const void* b, unsigned short* h) {
    __shared__ float Wl[32 * 64];
    __shared__ float xl[16][32];
    if (*flag) dense0_body<true>(x, W, b, h, Wl, xl);
    else       dense0_body<false>(x, W, b, h, Wl, xl);
}

// ---------------- aggregation: 16 lanes/node, per-lane scalar accumulators --
// (r19-proven 2-edge pipeline) h rows = 64 bf16 = 16 uint2. Group of 16
// lanes owns one node; lane j owns channel quad 4j..4j+3. Scalar per-lane
// accumulators across all edges -> no butterfly, no shfl.

__device__ __forceinline__ float4 agg16(int p, int d,
                                        const int* __restrict__ csr_src,
                                        const float* __restrict__ ew,
                                        const uint2* __restrict__ hu2,
                                        int j) {
    float a0 = 0.f, a1 = 0.f, a2 = 0.f, a3 = 0.f;
    int i0 = 0, i1 = 0;
    float e0 = 0.f, e1 = 0.f;
    if (d > 0) { i0 = csr_src[p]; e0 = ew[p]; }
    if (d > 1) { i1 = csr_src[p + 1]; e1 = ew[p + 1]; }
    int rem = d;
    while (rem > 0) {
        int n0 = 0, n1 = 0;
        float f0 = 0.f, f1 = 0.f;
        if (rem > 2) { n0 = csr_src[p + 2]; f0 = ew[p + 2]; }
        if (rem > 3) { n1 = csr_src[p + 3]; f1 = ew[p + 3]; }
        uint2 g0 = hu2[(size_t)i0 * 16 + j];
        uint2 g1 = hu2[(size_t)i1 * 16 + j];   // rem==1: i1=0,e1=0 -> adds 0
        a0 = fmaf(e0, __uint_as_float(g0.x << 16), a0);
        a1 = fmaf(e0, __uint_as_float(g0.x & 0xffff0000u), a1);
        a2 = fmaf(e0, __uint_as_float(g0.y << 16), a2);
        a3 = fmaf(e0, __uint_as_float(g0.y & 0xffff0000u), a3);
        a0 = fmaf(e1, __uint_as_float(g1.x << 16), a0);
        a1 = fmaf(e1, __uint_as_float(g1.x & 0xffff0000u), a1);
        a2 = fmaf(e1, __uint_as_float(g1.y << 16), a2);
        a3 = fmaf(e1, __uint_as_float(g1.y & 0xffff0000u), a3);
        i0 = n0; e0 = f0; i1 = n1; e1 = f1;
        p += 2; rem -= 2;
    }
    return make_float4(fmaxf(a0, 0.f), fmaxf(a1, 0.f), fmaxf(a2, 0.f), fmaxf(a3, 0.f));
}

// ---------------- fused: x = relu(agg(h_in)); h_out = x @ W + b ----------------
// 16 nodes/block via degree-sorted perm (4 waves x 4 groups); LDS 20KB

template <bool BF>
__device__ __forceinline__ void fuse_body(const int* row_start, const int* deg,
                                          const int* __restrict__ perm,
                                          const int* __restrict__ csr_src,
                                          const float* __restrict__ ew,
                                          const uint2* __restrict__ hu2,
                                          const void* W, int Woff, const void* b, int boff,
                                          unsigned short* h_out,
                                          float* Wl, float (*xs)[64]) {
    int t = threadIdx.x, w = t >> 6, lane = t & 63;
    for (int i = t; i < 64 * 64; i += 256) Wl[i] = LD<BF>(W, Woff + i);

    int g = lane >> 4, j = lane & 15;
    int idx = w * 4 + g;
    int base = blockIdx.x * 16;            // grid exact: 6250*16 = 100000
    int vg = perm[base + idx];             // degree-sorted node id
    float4 r = agg16(row_start[vg], deg[vg], csr_src, ew, hu2, j);
    *(float4*)&xs[idx][4 * j] = r;   // relu already applied
    __syncthreads();

    float bias = LD<BF>(b, boff + lane);
    float A0 = bias, A1 = bias, A2 = bias, A3 = bias;
    for (int k = 0; k < 64; k += 4) {
        float w0 = Wl[(k + 0) * 64 + lane];
        float w1 = Wl[(k + 1) * 64 + lane];
        float w2 = Wl[(k + 2) * 64 + lane];
        float w3 = Wl[(k + 3) * 64 + lane];
        float4 x0 = *(const float4*)&xs[w * 4 + 0][k];   // lane-uniform: LDS broadcast
        float4 x1 = *(const float4*)&xs[w * 4 + 1][k];
        float4 x2 = *(const float4*)&xs[w * 4 + 2][k];
        float4 x3 = *(const float4*)&xs[w * 4 + 3][k];
        A0 = fmaf(x0.x, w0, A0); A0 = fmaf(x0.y, w1, A0); A0 = fmaf(x0.z, w2, A0); A0 = fmaf(x0.w, w3, A0);
        A1 = fmaf(x1.x, w0, A1); A1 = fmaf(x1.y, w1, A1); A1 = fmaf(x1.z, w2, A1); A1 = fmaf(x1.w, w3, A1);
        A2 = fmaf(x2.x, w0, A2); A2 = fmaf(x2.y, w1, A2); A2 = fmaf(x2.z, w2, A2); A2 = fmaf(x2.w, w3, A2);
        A3 = fmaf(x3.x, w0, A3); A3 = fmaf(x3.y, w1, A3); A3 = fmaf(x3.z, w2, A3); A3 = fmaf(x3.w, w3, A3);
    }
    int vp0 = perm[base + w * 4 + 0];
    int vp1 = perm[base + w * 4 + 1];
    int vp2 = perm[base + w * 4 + 2];
    int vp3 = perm[base + w * 4 + 3];
    h_out[(size_t)vp0 * 64 + lane] = f2bf(A0);
    h_out[(size_t)vp1 * 64 + lane] = f2bf(A1);
    h_out[(size_t)vp2 * 64 + lane] = f2bf(A2);
    h_out[(size_t)vp3 * 64 + lane] = f2bf(A3);
}

__global__ void k_fuse(const int* __restrict__ flag,
                       const int* row_start, const int* deg, const int* perm,
                       const int* __restrict__ csr_src, const float* __restrict__ ew,
                       const void* hu,
                       const void* W, int Woff, const void* b, int boff,
                       unsigned short* h_out) {
    __shared__ float Wl[64 * 64];
    __shared__ float xs[16][64];
    if (*flag)
        fuse_body<true>(row_start, deg, perm, csr_src, ew, (const uint2*)hu,
                        W, Woff, b, boff, h_out, Wl, xs);
    else
        fuse_body<false>(row_start, deg, perm, csr_src, ew, (const uint2*)hu,
                         W, Woff, b, boff, h_out, Wl, xs);
}

// ---------------- fused final: x3 = relu(agg(h3)); heads -> out ---------------
// 16 nodes/block via perm (4 waves x 4 groups)

template <bool BF>
__device__ __forceinline__ void fuse_heads_body(
        const int* row_start, const int* deg, const int* __restrict__ perm,
        const int* __restrict__ csr_src, const float* __restrict__ ew,
        const uint2* __restrict__ hu2,
        const void* rh1w, const void* rh1b, const void* rh2w, const void* rh2b,
        const void* meanw, const void* meanb, const void* stdw, const void* stdb,
        const void* cls1w, const void* cls1b, const void* cls2w, const void* cls2b,
        void* __restrict__ out,
        float* s_rh1, float* s_cls1, float* s_rh2, float* s_cls2,
        float* s_rh1b, float* s_cls1b, float* s_rh2b, float* s_mw, float* s_sw,
        float* s_c2b, float* s_msb,
        float (*xs)[64], float (*r1)[32], float (*c1h)[32], float (*r2)[16]) {
    int t = threadIdx.x, w = t >> 6, lane = t & 63;
    for (int i = t; i < 2048; i += 256) { s_rh1[i] = LD<BF>(rh1w, i); s_cls1[i] = LD<BF>(cls1w, i); }
    for (int i = t; i < 512; i += 256) s_rh2[i] = LD<BF>(rh2w, i);
    if (t < 64) s_cls2[t] = LD<BF>(cls2w, t);
    if (t < 32) { s_rh1b[t] = LD<BF>(rh1b, t); s_cls1b[t] = LD<BF>(cls1b, t); }
    else if (t < 48) { int i = t - 32; s_rh2b[i] = LD<BF>(rh2b, i); s_mw[i] = LD<BF>(meanw, i); s_sw[i] = LD<BF>(stdw, i); }
    else if (t == 48) { s_msb[0] = LD<BF>(meanb, 0); s_msb[1] = LD<BF>(stdb, 0); }
    else if (t == 49) { s_c2b[0] = LD<BF>(cls2b, 0); s_c2b[1] = LD<BF>(cls2b, 1); }

    int g = lane >> 4, j = lane & 15;
    int idx0 = w * 4 + g;
    int base = blockIdx.x * 16;
    int vg = perm[base + idx0];
    float4 r = agg16(row_start[vg], deg[vg], csr_src, ew, hu2, j);
    *(float4*)&xs[idx0][4 * j] = r;
    __syncthreads();

    #pragma unroll
    for (int n = 0; n < 4; n++) {
        int idx = w * 4 + n;
        int c = lane & 31;
        const float* Wp = (lane < 32) ? s_rh1 : s_cls1;
        float a = (lane < 32) ? s_rh1b[c] : s_cls1b[c];
        #pragma unroll 8
        for (int k = 0; k < 64; k++) a = fmaf(xs[idx][k], Wp[k * 32 + c], a);
        a = fmaxf(a, 0.f);
        if (lane < 32) r1[idx][c] = a; else c1h[idx][c] = a;
    }
    __syncthreads();

    #pragma unroll
    for (int n = 0; n < 4; n++) {
        int idx = w * 4 + n;
        if (lane < 16) {
            float a = s_rh2b[lane];
            #pragma unroll
            for (int k = 0; k < 32; k++) a = fmaf(r1[idx][k], s_rh2[k * 16 + lane], a);
            r2[idx][lane] = fmaxf(a, 0.f);
        }
    }
    __syncthreads();

    #pragma unroll
    for (int n = 0; n < 4; n++) {
        int idx = w * 4 + n;
        int v = perm[base + idx];
        if (lane == 0) {
            float m = s_msb[0];
            #pragma unroll
            for (int k = 0; k < 16; k++) m = fmaf(r2[idx][k], s_mw[k], m);
            if (BF) ((unsigned short*)out)[v] = f2bf(m); else ((float*)out)[v] = m;
        } else if (lane == 1) {
            float sv = s_msb[1];
            #pragma unroll
            for (int k = 0; k < 16; k++) sv = fmaf(r2[idx][k], s_sw[k], sv);
            float sp = fmaxf(sv, 0.f) + log1pf(expf(-fabsf(sv)));   // stable softplus
            if (BF) ((unsigned short*)out)[N_NODES + v] = f2bf(sp); else ((float*)out)[N_NODES + v] = sp;
        } else if (lane < 4) {
            int jj = lane - 2;
            float a = s_c2b[jj];
            #pragma unroll
            for (int k = 0; k < 32; k++) a = fmaf(c1h[idx][k], s_cls2[k * 2 + jj], a);
            size_t pos = (size_t)2 * N_NODES + (size_t)v * 2 + jj;
            if (BF) ((unsigned short*)out)[pos] = f2bf(a); else ((float*)out)[pos] = a;
        }
    }
}

__global__ void k_fuse_heads(const int* __restrict__ flag,
                             const int* row_start, const int* deg, const int* perm,
                             const int* __restrict__ csr_src, const float* __restrict__ ew,
                             const void* hu,
                             const void* rh1w, const void* rh1b, const void* rh2w, const void* rh2b,
                             const void* meanw, const void* meanb, const void* stdw, const void* stdb,
                             const void* cls1w, const void* cls1b, const void* cls2w, const void* cls2b,
                             void* out) {
    __shared__ float s_rh1[64 * 32], s_cls1[64 * 32], s_rh2[32 * 16], s_cls2[32 * 2];
    __shared__ float s_rh1b[32], s_cls1b[32], s_rh2b[16], s_mw[16], s_sw[16], s_c2b[2], s_msb[2];
    __shared__ float xs[16][64], r1[16][32], c1h[16][32], r2[16][16];
    if (*flag)
        fuse_heads_body<true>(row_start, deg, perm, csr_src, ew, (const uint2*)hu,
                              rh1w, rh1b, rh2w, rh2b, meanw, meanb, stdw, stdb,
                              cls1w, cls1b, cls2w, cls2b, out,
                              s_rh1, s_cls1, s_rh2, s_cls2, s_rh1b, s_cls1b, s_rh2b,
                              s_mw, s_sw, s_c2b, s_msb, xs, r1, c1h, r2);
    else
        fuse_heads_body<false>(row_start, deg, perm, csr_src, ew, (const uint2*)hu,
                               rh1w, rh1b, rh2w, rh2b, meanw, meanb, stdw, stdb,
                               cls1w, cls1b, cls2w, cls2b, out,
                               s_rh1, s_cls1, s_rh2, s_cls2, s_rh1b, s_cls1b, s_rh2b,
                               s_mw, s_sw, s_c2b, s_msb, xs, r1, c1h, r2);
}

// ---------------- launch ----------------

extern "C" void kernel_launch(void* const* d_in, const int* in_sizes, int n_in,
                              void* d_out, int out_size, void* d_ws, size_t ws_size,
                              hipStream_t stream) {
    const void* x_in  = d_in[0];
    const int* ei     = (const int*)d_in[1];
    const void* ea    = d_in[2];
    const void* W0    = d_in[3];
    const void* b0    = d_in[4];
    const void* Ws    = d_in[5];
    const void* bs    = d_in[6];
    const void* ew1   = d_in[7];
    const void* eb1   = d_in[8];
    const void* ew2   = d_in[9];
    const void* eb2   = d_in[10];
    const void* rh1w  = d_in[11];
    const void* rh1b  = d_in[12];
    const void* rh2w  = d_in[13];
    const void* rh2b  = d_in[14];
    const void* meanw = d_in[15];
    const void* meanb = d_in[16];
    const void* stdw  = d_in[17];
    const void* stdb  = d_in[18];
    const void* cls1w = d_in[19];
    const void* cls1b = d_in[20];
    const void* cls2w = d_in[21];
    const void* cls2b = d_in[22];

    char* wsp = (char*)d_ws;
    auto alloc = [&](size_t bytes) -> char* {
        char* p = wsp;
        wsp += (bytes + 255) & ~(size_t)255;
        return p;
    };
    // footprint ~60 MB (< 78.2 MB proven):
    //   staging (<=25.6 MB) dead after k_ew -> aliased with hA+hB (12.8+12.8)
    int* flag       = (int*)alloc(4);
    int* deg        = (int*)alloc((size_t)N_NODES * 4);
    int* row_start  = (int*)alloc((size_t)N_NODES * 4);
    int* cursor     = (int*)alloc((size_t)N_NODES * 4);
    int* bsum       = (int*)alloc((size_t)NB_SCAN * 4);
    int* boff       = (int*)alloc((size_t)NB_SCAN * 4);
    int* blkhist    = (int*)alloc((size_t)NB_SCAN * 256 * 4);
    int* bincur     = (int*)alloc(256 * 4);
    int* perm       = (int*)alloc((size_t)N_NODES * 4);
    int* csr_src    = (int*)alloc((size_t)N_EDGES * 4);
    float* ew4      = (float*)alloc((size_t)4 * N_EDGES * 4);
    char* hreg      = alloc((size_t)N_EDGES * 16);       // union region, 25.6 MB
    void* staging   = (void*)hreg;
    unsigned short* hA = (unsigned short*)hreg;
    unsigned short* hB = (unsigned short*)(hreg + (size_t)N_NODES * 64 * 2);

    k_detect<<<1, 256, 0, stream>>>((const unsigned*)x_in, flag);
    hipMemsetAsync(deg, 0, (size_t)N_NODES * 4, stream);
    k_hist<<<6250, 256, 0, stream>>>(ei, deg);
    k_scan_partial<<<NB_SCAN, 256, 0, stream>>>(deg, bsum);
    k_scan_mid<<<1, 512, 0, stream>>>(bsum, boff);
    k_scan_final<<<NB_SCAN, 256, 0, stream>>>(deg, boff, row_start, cursor);
    // degree counting sort -> perm
    k_deg_hist<<<NB_SCAN, 256, 0, stream>>>(deg, blkhist);
    k_bin_scan<<<1, 256, 0, stream>>>(blkhist, bincur);
    k_perm<<<NB_SCAN, 256, 0, stream>>>(deg, bincur, perm);

    k_scatter<<<6250, 256, 0, stream>>>(flag, ei, ea, cursor, staging);
    k_ew<<<6250, 256, 0, stream>>>(flag, staging, ew1, eb1, ew2, eb2, csr_src, ew4);

    // h0 = x_in @ W0 + b0   (hA clobbers staging region -- dead after k_ew)
    k_dense0<<<6250, 256, 0, stream>>>(flag, x_in, W0, b0, hA);

    unsigned short* hin = hA;
    unsigned short* hout = hB;
    for (int l = 0; l < 3; l++) {
        k_fuse<<<6250, 256, 0, stream>>>(flag, row_start, deg, perm, csr_src,
                                         ew4 + (size_t)l * N_EDGES, hin,
                                         Ws, l * 64 * 64, bs, l * 64, hout);
        unsigned short* tmp = hin; hin = hout; hout = tmp;
    }
    k_fuse_heads<<<6250, 256, 0, stream>>>(flag, row_start, deg, perm, csr_src,
                                           ew4 + (size_t)3 * N_EDGES, hin,
                                           rh1w, rh1b, rh2w, rh2b, meanw, meanb,
                                           stdw, stdb, cls1w, cls1b, cls2w, cls2b,
                                           d_out);
}

// Round 8
// 604.404 us; speedup vs baseline: 1.4473x; 1.4473x over previous
//
#include <hip/hip_runtime.h>
#include <stdint.h>

#define N_NODES 100000
#define N_EDGES 1600000
#define NB_SCAN 391   // ceil(N_NODES/256)

// Round 23. r22 (874us) post-mortem: k_perm = 263us of pure atomic contention
// (100K atomicAdds on 256 global bins); degree-sort also hurt the fuse
// kernels (perm indirection + lost stream locality): pipeline-minus-perm
// 611 > 596. Degree sort dropped entirely.
// r23 = r19 (596us proven) + two surviving deltas:
// (1) BF staging = 8B records {src, a1|a0 bf16 bits} (bitwise-exact) ->
//     12.8MB staging, 8 rec/line -> scatter write-line traffic ~101->~65MB.
// (2) csr_src holds BYTE offsets (src*128) -> agg gather addr = base+off+j*8,
//     no per-gather multiply. Numerics bit-identical -> absmax 0.0625.

__device__ __forceinline__ float bf2f(unsigned short s) {
    return __uint_as_float(((unsigned)s) << 16);
}
__device__ __forceinline__ unsigned short f2bf(float f) {
    unsigned u = __float_as_uint(f);
    u += 0x7fffu + ((u >> 16) & 1u);
    return (unsigned short)(u >> 16);
}
template <bool BF16>
__device__ __forceinline__ float LD(const void* p, size_t i) {
    if (BF16) return bf2f(((const unsigned short*)p)[i]);
    return ((const float*)p)[i];
}

// ---------------- dtype detection (proven) ----------------
__global__ void k_detect(const unsigned* __restrict__ xw, int* __restrict__ flag) {
    __shared__ int tot;
    if (threadIdx.x == 0) tot = 0;
    __syncthreads();
    int hit = 0;
    for (int i = threadIdx.x; i < 1024; i += 256) {
        unsigned e = (xw[i] >> 7) & 0xFFu;
        if (e >= 110u && e <= 135u) hit++;
    }
    atomicAdd(&tot, hit);
    __syncthreads();
    if (threadIdx.x == 0) *flag = (tot >= 512) ? 1 : 0;
}

// ---------------- CSR build ----------------

__global__ void k_hist(const int* __restrict__ ei, int* __restrict__ deg) {
    int e = blockIdx.x * 256 + threadIdx.x;
    if (e < N_EDGES) atomicAdd(&deg[ei[N_EDGES + e]], 1);
}

__global__ void k_scan_partial(const int* __restrict__ deg, int* __restrict__ bsum) {
    int t = threadIdx.x;
    int i = blockIdx.x * 256 + t;
    int v = (i < N_NODES) ? deg[i] : 0;
    for (int off = 32; off > 0; off >>= 1) v += __shfl_down(v, off, 64);
    __shared__ int ws4[4];
    if ((t & 63) == 0) ws4[t >> 6] = v;
    __syncthreads();
    if (t == 0) bsum[blockIdx.x] = ws4[0] + ws4[1] + ws4[2] + ws4[3];
}

__global__ void k_scan_mid(const int* __restrict__ bsum, int* __restrict__ boff) {
    __shared__ int s[512];
    int t = threadIdx.x;
    int v = (t < NB_SCAN) ? bsum[t] : 0;
    s[t] = v;
    __syncthreads();
    for (int off = 1; off < 512; off <<= 1) {
        int x = (t >= off) ? s[t - off] : 0;
        __syncthreads();
        s[t] += x;
        __syncthreads();
    }
    if (t < NB_SCAN) boff[t] = s[t] - v;   // exclusive
}

__global__ void k_scan_final(const int* __restrict__ deg, const int* __restrict__ boff,
                             int* __restrict__ row_start, int* __restrict__ cursor) {
    __shared__ int s[256];
    int t = threadIdx.x;
    int i = blockIdx.x * 256 + t;
    int v = (i < N_NODES) ? deg[i] : 0;
    s[t] = v;
    __syncthreads();
    for (int off = 1; off < 256; off <<= 1) {
        int x = (t >= off) ? s[t - off] : 0;
        __syncthreads();
        s[t] += x;
        __syncthreads();
    }
    if (i < N_NODES) {
        int rs = boff[blockIdx.x] + s[t] - v;
        row_start[i] = rs;
        cursor[i] = rs;
    }
}

// ---------------- CSR scatter ----------------
// BF path: 8B record {src, (a1<<16)|a0 raw bf16 bits} - bitwise exact.
// FP path: 16B record {src, a0bits, a1bits, 0}.

__device__ void scatter_bf(const int* __restrict__ ei, const unsigned short* __restrict__ ea,
                           int* __restrict__ cursor, uint2* __restrict__ rec8) {
    int e = blockIdx.x * 256 + threadIdx.x;   // grid exact: 6250*256 = 1.6M
    int s = ei[e];
    int d = ei[N_EDGES + e];
    unsigned a0 = ea[(size_t)e * 2];
    unsigned a1 = ea[(size_t)e * 2 + 1];
    int slot = atomicAdd(&cursor[d], 1);
    rec8[slot] = make_uint2((unsigned)s, a0 | (a1 << 16));
}

__device__ void scatter_fp(const int* __restrict__ ei, const float* __restrict__ ea,
                           int* __restrict__ cursor, uint4* __restrict__ rec16) {
    int e = blockIdx.x * 256 + threadIdx.x;
    int s = ei[e];
    int d = ei[N_EDGES + e];
    float a0 = ea[(size_t)e * 2];
    float a1 = ea[(size_t)e * 2 + 1];
    int slot = atomicAdd(&cursor[d], 1);
    rec16[slot] = make_uint4((unsigned)s, __float_as_uint(a0), __float_as_uint(a1), 0u);
}

__global__ void k_scatter(const int* __restrict__ flag, const int* ei, const void* ea,
                          int* cursor, void* staging) {
    if (*flag) scatter_bf(ei, (const unsigned short*)ea, cursor, (uint2*)staging);
    else       scatter_fp(ei, (const float*)ea, cursor, (uint4*)staging);
}

// ---------------- edge-MLP pass: slot-ordered, fully coalesced ----------------
// Writes csr_off = src*128 (byte offset of h row; 100000*128 < 2^31).

template <bool BF>
__device__ __forceinline__ void ew_body(const void* __restrict__ staging,
                                        const void* ew1, const void* eb1,
                                        const void* ew2, const void* eb2,
                                        int* __restrict__ csr_off,
                                        float* __restrict__ ew4,
                                        float (*w1)[2][16], float (*b1)[16],
                                        float (*w2)[16], float* b2) {
    int t = threadIdx.x;
    if (t < 128) ((float*)w1)[t] = LD<BF>(ew1, t);
    else if (t < 192) ((float*)b1)[t - 128] = LD<BF>(eb1, t - 128);
    else ((float*)w2)[t - 192] = LD<BF>(ew2, t - 192);
    if (t < 4) b2[t] = LD<BF>(eb2, t);
    __syncthreads();

    int e = blockIdx.x * 256 + t;   // grid exact: 6250*256 = 1.6M
    float a0, a1;
    if (BF) {
        uint2 u = ((const uint2*)staging)[e];
        csr_off[e] = (int)(u.x * 128u);
        a0 = bf2f((unsigned short)(u.y & 0xffffu));
        a1 = bf2f((unsigned short)(u.y >> 16));
    } else {
        uint4 u = ((const uint4*)staging)[e];
        csr_off[e] = (int)(u.x * 128u);
        a0 = __uint_as_float(u.y);
        a1 = __uint_as_float(u.z);
    }
    #pragma unroll
    for (int l = 0; l < 4; l++) {
        float z = b2[l];
        #pragma unroll
        for (int q = 0; q < 16; q++) {
            float hj = fmaf(a0, w1[l][0][q], fmaf(a1, w1[l][1][q], b1[l][q]));
            z = fmaf(fmaxf(hj, 0.f), w2[l][q], z);
        }
        ew4[(size_t)l * N_EDGES + e] = 1.f / (1.f + expf(-z));
    }
}

__global__ void k_ew(const int* __restrict__ flag, const void* __restrict__ staging,
                     const void* ew1, const void* eb1, const void* ew2, const void* eb2,
                     int* csr_off, float* ew4) {
    __shared__ float w1[4][2][16], b1[4][16], w2[4][16], b2[4];
    if (*flag) ew_body<true>(staging, ew1, eb1, ew2, eb2, csr_off, ew4, w1, b1, w2, b2);
    else       ew_body<false>(staging, ew1, eb1, ew2, eb2, csr_off, ew4, w1, b1, w2, b2);
}

// ---------------- layer 0 dense ----------------

template <bool BF>
__device__ __forceinline__ void dense0_body(const void* __restrict__ x,
                                            const void* __restrict__ W,
                                            const void* __restrict__ b,
                                            unsigned short* __restrict__ h,
                                            float* Wl, float (*xl)[32]) {
    int t = threadIdx.x, w = t >> 6, lane = t & 63;
    for (int i = t; i < 32 * 64; i += 256) Wl[i] = LD<BF>(W, i);
    int v0 = blockIdx.x * 16 + w * 4;
    if (lane < 32) {
        #pragma unroll
        for (int n = 0; n < 4; n++)
            xl[w * 4 + n][lane] = LD<BF>(x, (size_t)(v0 + n) * 32 + lane);
    }
    __syncthreads();
    float bias = LD<BF>(b, lane);
    float a0 = bias, a1 = bias, a2 = bias, a3 = bias;
    #pragma unroll 8
    for (int k = 0; k < 32; k++) {
        float wv = Wl[k * 64 + lane];
        a0 = fmaf(xl[w * 4 + 0][k], wv, a0);
        a1 = fmaf(xl[w * 4 + 1][k], wv, a1);
        a2 = fmaf(xl[w * 4 + 2][k], wv, a2);
        a3 = fmaf(xl[w * 4 + 3][k], wv, a3);
    }
    h[(size_t)(v0 + 0) * 64 + lane] = f2bf(a0);
    h[(size_t)(v0 + 1) * 64 + lane] = f2bf(a1);
    h[(size_t)(v0 + 2) * 64 + lane] = f2bf(a2);
    h[(size_t)(v0 + 3) * 64 + lane] = f2bf(a3);
}

__global__ void k_dense0(const int* __restrict__ flag, const void* x, const void* W,
                         const void* b, unsigned short* h) {
    __shared__ float Wl[32 * 64];
    __shared__ float xl[16][32];
    if (*flag) dense0_body<true>(x, W, b, h, Wl, xl);
    else       dense0_body<false>(x, W, b, h, Wl, xl);
}

// ---------------- aggregation: 16 lanes/node, per-lane scalar accumulators --
// (r19-proven 2-edge pipeline) csr_off holds byte offsets (src*128); lane j
// reads *(uint2*)(hb + off + j*8) -> no multiply in gather address.

__device__ __forceinline__ float4 agg16(int p, int d,
                                        const int* __restrict__ csr_off,
                                        const float* __restrict__ ew,
                                        const char* __restrict__ hb,
                                        int j8) {
    float a0 = 0.f, a1 = 0.f, a2 = 0.f, a3 = 0.f;
    int o0 = 0, o1 = 0;
    float e0 = 0.f, e1 = 0.f;
    if (d > 0) { o0 = csr_off[p]; e0 = ew[p]; }
    if (d > 1) { o1 = csr_off[p + 1]; e1 = ew[p + 1]; }
    int rem = d;
    while (rem > 0) {
        int n0 = 0, n1 = 0;
        float f0 = 0.f, f1 = 0.f;
        if (rem > 2) { n0 = csr_off[p + 2]; f0 = ew[p + 2]; }
        if (rem > 3) { n1 = csr_off[p + 3]; f1 = ew[p + 3]; }
        uint2 g0 = *(const uint2*)(hb + (unsigned)(o0 + j8));
        uint2 g1 = *(const uint2*)(hb + (unsigned)(o1 + j8));   // rem==1: o1=0,e1=0
        a0 = fmaf(e0, __uint_as_float(g0.x << 16), a0);
        a1 = fmaf(e0, __uint_as_float(g0.x & 0xffff0000u), a1);
        a2 = fmaf(e0, __uint_as_float(g0.y << 16), a2);
        a3 = fmaf(e0, __uint_as_float(g0.y & 0xffff0000u), a3);
        a0 = fmaf(e1, __uint_as_float(g1.x << 16), a0);
        a1 = fmaf(e1, __uint_as_float(g1.x & 0xffff0000u), a1);
        a2 = fmaf(e1, __uint_as_float(g1.y << 16), a2);
        a3 = fmaf(e1, __uint_as_float(g1.y & 0xffff0000u), a3);
        o0 = n0; e0 = f0; o1 = n1; e1 = f1;
        p += 2; rem -= 2;
    }
    return make_float4(fmaxf(a0, 0.f), fmaxf(a1, 0.f), fmaxf(a2, 0.f), fmaxf(a3, 0.f));
}

// ---------------- fused: x = relu(agg(h_in)); h_out = x @ W + b ----------------
// 16 nodes/block (4 waves x 4 groups x 1 node); LDS 20KB

template <bool BF>
__device__ __forceinline__ void fuse_body(const int* row_start, const int* deg,
                                          const int* __restrict__ csr_off,
                                          const float* __restrict__ ew,
                                          const char* __restrict__ hb,
                                          const void* W, int Woff, const void* b, int boff,
                                          unsigned short* h_out,
                                          float* Wl, float (*xs)[64]) {
    int t = threadIdx.x, w = t >> 6, lane = t & 63;
    for (int i = t; i < 64 * 64; i += 256) Wl[i] = LD<BF>(W, Woff + i);

    int g = lane >> 4, j = lane & 15;
    int idx = w * 4 + g;
    int v = blockIdx.x * 16 + idx;   // grid exact: 6250*16 = 100000
    float4 r = agg16(row_start[v], deg[v], csr_off, ew, hb, j * 8);
    *(float4*)&xs[idx][4 * j] = r;   // relu already applied
    __syncthreads();

    float bias = LD<BF>(b, boff + lane);
    float A0 = bias, A1 = bias, A2 = bias, A3 = bias;
    for (int k = 0; k < 64; k += 4) {
        float w0 = Wl[(k + 0) * 64 + lane];
        float w1 = Wl[(k + 1) * 64 + lane];
        float w2 = Wl[(k + 2) * 64 + lane];
        float w3 = Wl[(k + 3) * 64 + lane];
        float4 x0 = *(const float4*)&xs[w * 4 + 0][k];   // lane-uniform: LDS broadcast
        float4 x1 = *(const float4*)&xs[w * 4 + 1][k];
        float4 x2 = *(const float4*)&xs[w * 4 + 2][k];
        float4 x3 = *(const float4*)&xs[w * 4 + 3][k];
        A0 = fmaf(x0.x, w0, A0); A0 = fmaf(x0.y, w1, A0); A0 = fmaf(x0.z, w2, A0); A0 = fmaf(x0.w, w3, A0);
        A1 = fmaf(x1.x, w0, A1); A1 = fmaf(x1.y, w1, A1); A1 = fmaf(x1.z, w2, A1); A1 = fmaf(x1.w, w3, A1);
        A2 = fmaf(x2.x, w0, A2); A2 = fmaf(x2.y, w1, A2); A2 = fmaf(x2.z, w2, A2); A2 = fmaf(x2.w, w3, A2);
        A3 = fmaf(x3.x, w0, A3); A3 = fmaf(x3.y, w1, A3); A3 = fmaf(x3.z, w2, A3); A3 = fmaf(x3.w, w3, A3);
    }
    int v0 = blockIdx.x * 16 + w * 4;
    h_out[(size_t)(v0 + 0) * 64 + lane] = f2bf(A0);
    h_out[(size_t)(v0 + 1) * 64 + lane] = f2bf(A1);
    h_out[(size_t)(v0 + 2) * 64 + lane] = f2bf(A2);
    h_out[(size_t)(v0 + 3) * 64 + lane] = f2bf(A3);
}

__global__ void k_fuse(const int* __restrict__ flag,
                       const int* row_start, const int* deg,
                       const int* __restrict__ csr_off, const float* __restrict__ ew,
                       const void* hu,
                       const void* W, int Woff, const void* b, int boff,
                       unsigned short* h_out) {
    __shared__ float Wl[64 * 64];
    __shared__ float xs[16][64];
    if (*flag)
        fuse_body<true>(row_start, deg, csr_off, ew, (const char*)hu,
                        W, Woff, b, boff, h_out, Wl, xs);
    else
        fuse_body<false>(row_start, deg, csr_off, ew, (const char*)hu,
                         W, Woff, b, boff, h_out, Wl, xs);
}

// ---------------- fused final: x3 = relu(agg(h3)); heads -> out ---------------
// 16 nodes/block (4 waves x 4 groups); phases identical to r19

template <bool BF>
__device__ __forceinline__ void fuse_heads_body(
        const int* row_start, const int* deg,
        const int* __restrict__ csr_off, const float* __restrict__ ew,
        const char* __restrict__ hb,
        const void* rh1w, const void* rh1b, const void* rh2w, const void* rh2b,
        const void* meanw, const void* meanb, const void* stdw, const void* stdb,
        const void* cls1w, const void* cls1b, const void* cls2w, const void* cls2b,
        void* __restrict__ out,
        float* s_rh1, float* s_cls1, float* s_rh2, float* s_cls2,
        float* s_rh1b, float* s_cls1b, float* s_rh2b, float* s_mw, float* s_sw,
        float* s_c2b, float* s_msb,
        float (*xs)[64], float (*r1)[32], float (*c1h)[32], float (*r2)[16]) {
    int t = threadIdx.x, w = t >> 6, lane = t & 63;
    for (int i = t; i < 2048; i += 256) { s_rh1[i] = LD<BF>(rh1w, i); s_cls1[i] = LD<BF>(cls1w, i); }
    for (int i = t; i < 512; i += 256) s_rh2[i] = LD<BF>(rh2w, i);
    if (t < 64) s_cls2[t] = LD<BF>(cls2w, t);
    if (t < 32) { s_rh1b[t] = LD<BF>(rh1b, t); s_cls1b[t] = LD<BF>(cls1b, t); }
    else if (t < 48) { int i = t - 32; s_rh2b[i] = LD<BF>(rh2b, i); s_mw[i] = LD<BF>(meanw, i); s_sw[i] = LD<BF>(stdw, i); }
    else if (t == 48) { s_msb[0] = LD<BF>(meanb, 0); s_msb[1] = LD<BF>(stdb, 0); }
    else if (t == 49) { s_c2b[0] = LD<BF>(cls2b, 0); s_c2b[1] = LD<BF>(cls2b, 1); }

    int g = lane >> 4, j = lane & 15;
    int idx0 = w * 4 + g;
    int v00 = blockIdx.x * 16;
    float4 r = agg16(row_start[v00 + idx0], deg[v00 + idx0], csr_off, ew, hb, j * 8);
    *(float4*)&xs[idx0][4 * j] = r;
    __syncthreads();

    #pragma unroll
    for (int n = 0; n < 4; n++) {
        int idx = w * 4 + n;
        int c = lane & 31;
        const float* Wp = (lane < 32) ? s_rh1 : s_cls1;
        float a = (lane < 32) ? s_rh1b[c] : s_cls1b[c];
        #pragma unroll 8
        for (int k = 0; k < 64; k++) a = fmaf(xs[idx][k], Wp[k * 32 + c], a);
        a = fmaxf(a, 0.f);
        if (lane < 32) r1[idx][c] = a; else c1h[idx][c] = a;
    }
    __syncthreads();

    #pragma unroll
    for (int n = 0; n < 4; n++) {
        int idx = w * 4 + n;
        if (lane < 16) {
            float a = s_rh2b[lane];
            #pragma unroll
            for (int k = 0; k < 32; k++) a = fmaf(r1[idx][k], s_rh2[k * 16 + lane], a);
            r2[idx][lane] = fmaxf(a, 0.f);
        }
    }
    __syncthreads();

    #pragma unroll
    for (int n = 0; n < 4; n++) {
        int idx = w * 4 + n;
        int v = v00 + idx;
        if (lane == 0) {
            float m = s_msb[0];
            #pragma unroll
            for (int k = 0; k < 16; k++) m = fmaf(r2[idx][k], s_mw[k], m);
            if (BF) ((unsigned short*)out)[v] = f2bf(m); else ((float*)out)[v] = m;
        } else if (lane == 1) {
            float sv = s_msb[1];
            #pragma unroll
            for (int k = 0; k < 16; k++) sv = fmaf(r2[idx][k], s_sw[k], sv);
            float sp = fmaxf(sv, 0.f) + log1pf(expf(-fabsf(sv)));   // stable softplus
            if (BF) ((unsigned short*)out)[N_NODES + v] = f2bf(sp); else ((float*)out)[N_NODES + v] = sp;
        } else if (lane < 4) {
            int jj = lane - 2;
            float a = s_c2b[jj];
            #pragma unroll
            for (int k = 0; k < 32; k++) a = fmaf(c1h[idx][k], s_cls2[k * 2 + jj], a);
            size_t pos = (size_t)2 * N_NODES + (size_t)v * 2 + jj;
            if (BF) ((unsigned short*)out)[pos] = f2bf(a); else ((float*)out)[pos] = a;
        }
    }
}

__global__ void k_fuse_heads(const int* __restrict__ flag,
                             const int* row_start, const int* deg,
                             const int* __restrict__ csr_off, const float* __restrict__ ew,
                             const void* hu,
                             const void* rh1w, const void* rh1b, const void* rh2w, const void* rh2b,
                             const void* meanw, const void* meanb, const void* stdw, const void* stdb,
                             const void* cls1w, const void* cls1b, const void* cls2w, const void* cls2b,
                             void* out) {
    __shared__ float s_rh1[64 * 32], s_cls1[64 * 32], s_rh2[32 * 16], s_cls2[32 * 2];
    __shared__ float s_rh1b[32], s_cls1b[32], s_rh2b[16], s_mw[16], s_sw[16], s_c2b[2], s_msb[2];
    __shared__ float xs[16][64], r1[16][32], c1h[16][32], r2[16][16];
    if (*flag)
        fuse_heads_body<true>(row_start, deg, csr_off, ew, (const char*)hu,
                              rh1w, rh1b, rh2w, rh2b, meanw, meanb, stdw, stdb,
                              cls1w, cls1b, cls2w, cls2b, out,
                              s_rh1, s_cls1, s_rh2, s_cls2, s_rh1b, s_cls1b, s_rh2b,
                              s_mw, s_sw, s_c2b, s_msb, xs, r1, c1h, r2);
    else
        fuse_heads_body<false>(row_start, deg, csr_off, ew, (const char*)hu,
                               rh1w, rh1b, rh2w, rh2b, meanw, meanb, stdw, stdb,
                               cls1w, cls1b, cls2w, cls2b, out,
                               s_rh1, s_cls1, s_rh2, s_cls2, s_rh1b, s_cls1b, s_rh2b,
                               s_mw, s_sw, s_c2b, s_msb, xs, r1, c1h, r2);
}

// ---------------- launch ----------------

extern "C" void kernel_launch(void* const* d_in, const int* in_sizes, int n_in,
                              void* d_out, int out_size, void* d_ws, size_t ws_size,
                              hipStream_t stream) {
    const void* x_in  = d_in[0];
    const int* ei     = (const int*)d_in[1];
    const void* ea    = d_in[2];
    const void* W0    = d_in[3];
    const void* b0    = d_in[4];
    const void* Ws    = d_in[5];
    const void* bs    = d_in[6];
    const void* ew1   = d_in[7];
    const void* eb1   = d_in[8];
    const void* ew2   = d_in[9];
    const void* eb2   = d_in[10];
    const void* rh1w  = d_in[11];
    const void* rh1b  = d_in[12];
    const void* rh2w  = d_in[13];
    const void* rh2b  = d_in[14];
    const void* meanw = d_in[15];
    const void* meanb = d_in[16];
    const void* stdw  = d_in[17];
    const void* stdb  = d_in[18];
    const void* cls1w = d_in[19];
    const void* cls1b = d_in[20];
    const void* cls2w = d_in[21];
    const void* cls2b = d_in[22];

    char* wsp = (char*)d_ws;
    auto alloc = [&](size_t bytes) -> char* {
        char* p = wsp;
        wsp += (bytes + 255) & ~(size_t)255;
        return p;
    };
    // footprint ~59 MB (< 78.2 MB proven):
    //   staging (<=25.6 MB) dead after k_ew -> aliased with hA+hB (12.8+12.8)
    int* flag       = (int*)alloc(4);
    int* deg        = (int*)alloc((size_t)N_NODES * 4);
    int* row_start  = (int*)alloc((size_t)N_NODES * 4);
    int* cursor     = (int*)alloc((size_t)N_NODES * 4);
    int* bsum       = (int*)alloc((size_t)NB_SCAN * 4);
    int* boff       = (int*)alloc((size_t)NB_SCAN * 4);
    int* csr_off    = (int*)alloc((size_t)N_EDGES * 4);
    float* ew4      = (float*)alloc((size_t)4 * N_EDGES * 4);
    char* hreg      = alloc((size_t)N_EDGES * 16);       // union region, 25.6 MB
    void* staging   = (void*)hreg;
    unsigned short* hA = (unsigned short*)hreg;
    unsigned short* hB = (unsigned short*)(hreg + (size_t)N_NODES * 64 * 2);

    k_detect<<<1, 256, 0, stream>>>((const unsigned*)x_in, flag);
    hipMemsetAsync(deg, 0, (size_t)N_NODES * 4, stream);
    k_hist<<<6250, 256, 0, stream>>>(ei, deg);
    k_scan_partial<<<NB_SCAN, 256, 0, stream>>>(deg, bsum);
    k_scan_mid<<<1, 512, 0, stream>>>(bsum, boff);
    k_scan_final<<<NB_SCAN, 256, 0, stream>>>(deg, boff, row_start, cursor);
    k_scatter<<<6250, 256, 0, stream>>>(flag, ei, ea, cursor, staging);
    k_ew<<<6250, 256, 0, stream>>>(flag, staging, ew1, eb1, ew2, eb2, csr_off, ew4);

    // h0 = x_in @ W0 + b0   (hA clobbers staging region -- dead after k_ew)
    k_dense0<<<6250, 256, 0, stream>>>(flag, x_in, W0, b0, hA);

    unsigned short* hin = hA;
    unsigned short* hout = hB;
    for (int l = 0; l < 3; l++) {
        k_fuse<<<6250, 256, 0, stream>>>(flag, row_start, deg, csr_off,
                                         ew4 + (size_t)l * N_EDGES, hin,
                                         Ws, l * 64 * 64, bs, l * 64, hout);
        unsigned short* tmp = hin; hin = hout; hout = tmp;
    }
    k_fuse_heads<<<6250, 256, 0, stream>>>(flag, row_start, deg, csr_off,
                                           ew4 + (size_t)3 * N_EDGES, hin,
                                           rh1w, rh1b, rh2w, rh2b, meanw, meanb,
                                           stdw, stdb, cls1w, cls1b, cls2w, cls2b,
                                           d_out);
}